// Round 1
// baseline (216.397 us; speedup 1.0000x reference)
//
#include <hip/hip_runtime.h>
#include <stdint.h>

#define EMBED 1024
#define NH 16
#define HD 64
#define BATCH 2
#define SEQ 2048
#define MTOK (BATCH*SEQ)   // 4096

using bf8 = __attribute__((ext_vector_type(8))) short;   // 8 bf16 = one MFMA A/B frag
using f4  = __attribute__((ext_vector_type(4))) float;   // MFMA C/D frag
using u16x4 = __attribute__((ext_vector_type(4))) unsigned short;

__device__ __forceinline__ unsigned short f2bf(float f) {
  union { float f; uint32_t u; } v; v.f = f;
  uint32_t u = v.u;
  return (unsigned short)((u + 0x7FFFu + ((u >> 16) & 1u)) >> 16);  // RNE
}

__device__ __forceinline__ void gl2lds16(const void* g, void* l) {
  __builtin_amdgcn_global_load_lds(
      (const __attribute__((address_space(1))) void*)g,
      (__attribute__((address_space(3))) void*)l, 16, 0, 0);
}

// ---------------- prep: fp32 -> bf16 ----------------
__global__ __launch_bounds__(256) void conv_bf16(const float* __restrict__ x,
                                                 unsigned short* __restrict__ y) {
  int i = (blockIdx.x * 256 + threadIdx.x) * 4;
  float4 v = *(const float4*)(x + i);
  u16x4 o;
  o[0] = f2bf(v.x); o[1] = f2bf(v.y); o[2] = f2bf(v.z); o[3] = f2bf(v.w);
  *(u16x4*)(y + i) = o;
}

// ---------------- prep: transpose fp32 [K][N] -> bf16 [N][K] ----------------
__global__ __launch_bounds__(256) void transp_bf16(const float* __restrict__ W,
                                                   unsigned short* __restrict__ Wt,
                                                   int K, int N) {
  __shared__ float tl[64][65];
  int k0 = blockIdx.y * 64, n0 = blockIdx.x * 64;
  int tr = threadIdx.x >> 6, tc = threadIdx.x & 63;
#pragma unroll
  for (int i = 0; i < 16; i++) {
    int r = tr + i * 4;
    tl[r][tc] = W[(size_t)(k0 + r) * N + n0 + tc];
  }
  __syncthreads();
#pragma unroll
  for (int i = 0; i < 16; i++) {
    int r = tr + i * 4;
    Wt[(size_t)(n0 + r) * K + k0 + tc] = f2bf(tl[tc][r]);
  }
}

// ---------------- bf16 GEMM: C[M][N] = A[M][K] * Bt[N][K]^T + bias ----------------
// mode 0: scatter bf16 into qkv [3][B][H][T][D];  mode 1: fp32 row-major out
__global__ __launch_bounds__(256) void gemm_bt(const unsigned short* __restrict__ A,
                                               const unsigned short* __restrict__ Bt,
                                               const float* __restrict__ bias,
                                               void* __restrict__ Cout,
                                               int M, int N, int K, int mode) {
  const int tid = threadIdx.x;
  const int w = tid >> 6, lane = tid & 63;
  const int wm = w >> 1, wn = w & 1;                 // 2x2 waves, each 64x64
  const int m0 = blockIdx.y * 128, n0 = blockIdx.x * 128;

  __shared__ char smem[32768];
  char* Al = smem;              // [128 m][64 k] bf16, XOR-swizzled rows
  char* Bl = smem + 16384;      // [128 n][64 k] bf16, XOR-swizzled rows

  f4 acc[4][4] = {};

  for (int k0 = 0; k0 < K; k0 += 64) {
    __syncthreads();
#pragma unroll
    for (int i = 0; i < 4; i++) {
      int row = w * 8 + i * 32 + (lane >> 3);
      int col = ((lane & 7) * 8) ^ ((row & 7) << 3);   // pre-swizzled global source
      gl2lds16(A  + (size_t)(m0 + row) * K + k0 + col, Al + (w * 8 + i * 32) * 128);
      gl2lds16(Bt + (size_t)(n0 + row) * K + k0 + col, Bl + (w * 8 + i * 32) * 128);
    }
    __syncthreads();
#pragma unroll
    for (int ks = 0; ks < 2; ks++) {
      bf8 af[4], bfr[4];
#pragma unroll
      for (int mt = 0; mt < 4; mt++) {
        int rr = wm * 64 + mt * 16 + (lane & 15);
        af[mt] = *(const bf8*)(Al + rr * 128 + ((ks * 64 + (lane >> 4) * 16) ^ ((rr & 7) << 4)));
      }
#pragma unroll
      for (int nt = 0; nt < 4; nt++) {
        int rr = wn * 64 + nt * 16 + (lane & 15);
        bfr[nt] = *(const bf8*)(Bl + rr * 128 + ((ks * 64 + (lane >> 4) * 16) ^ ((rr & 7) << 4)));
      }
#pragma unroll
      for (int mt = 0; mt < 4; mt++)
#pragma unroll
        for (int nt = 0; nt < 4; nt++)
          acc[mt][nt] = __builtin_amdgcn_mfma_f32_16x16x32_bf16(af[mt], bfr[nt], acc[mt][nt], 0, 0, 0);
    }
  }

  if (mode == 0) {
    unsigned short* Q = (unsigned short*)Cout;   // [3][B][H][T][D]
#pragma unroll
    for (int nt = 0; nt < 4; nt++) {
      int n = n0 + wn * 64 + nt * 16 + (lane & 15);
      float bv = bias[n];
      int region = n >> 10, c = n & 1023, h = c >> 6, d = c & 63;
#pragma unroll
      for (int mt = 0; mt < 4; mt++) {
#pragma unroll
        for (int r = 0; r < 4; r++) {
          int m = m0 + wm * 64 + mt * 16 + (lane >> 4) * 4 + r;
          int b = m >> 11, t = m & 2047;
          size_t off = ((((size_t)region * 2 + b) * 16 + h) * 2048 + t) * 64 + d;
          Q[off] = f2bf(acc[mt][nt][r] + bv);
        }
      }
    }
  } else {
    float* O = (float*)Cout;
#pragma unroll
    for (int mt = 0; mt < 4; mt++) {
#pragma unroll
      for (int r = 0; r < 4; r++) {
        int m = m0 + wm * 64 + mt * 16 + (lane >> 4) * 4 + r;
#pragma unroll
        for (int nt = 0; nt < 4; nt++) {
          int n = n0 + wn * 64 + nt * 16 + (lane & 15);
          O[(size_t)m * N + n] = acc[mt][nt][r] + bias[n];
        }
      }
    }
  }
}

// ---------------- causal flash attention, bf16 MFMA ----------------
// grid: (qtile=T/64, BH). block 256 = 4 waves x 16 q-rows. KV tile = 64.
__global__ __launch_bounds__(256) void attn_kernel(const unsigned short* __restrict__ Qb,
                                                   const unsigned short* __restrict__ Kb,
                                                   const unsigned short* __restrict__ Vb,
                                                   unsigned short* __restrict__ Ob) {
  const int qtile = blockIdx.x;
  const int bh = blockIdx.y;
  const int tid = threadIdx.x;
  const int w = tid >> 6, lane = tid & 63;

  __shared__ char smem[24576];
  char* Kl = smem;                       // [64 key][64 d] swizzled
  char* Vl = smem + 8192;                // [64 d][64 key] swizzled (transposed)
  char* Pl = smem + 16384 + w * 2048;    // per-wave [16 q][64 key] swizzled

  const unsigned short* Qg = Qb + (size_t)bh * SEQ * HD;
  const unsigned short* Kg = Kb + (size_t)bh * SEQ * HD;
  const unsigned short* Vg = Vb + (size_t)bh * SEQ * HD;

  // Q fragments held in registers for the whole block row
  const int qrow_frag = qtile * 64 + w * 16 + (lane & 15);
  bf8 qfrag[2];
  {
    const unsigned short* qp = Qg + (size_t)qrow_frag * HD + ((lane >> 4) * 8);
    qfrag[0] = *(const bf8*)(qp);
    qfrag[1] = *(const bf8*)(qp + 32);
  }

  f4 acc_o[4] = {};                      // d-chunks; row=(lane>>4)*4+r, col=lane&15+16*dc
  float m_run[4], l_run[4];
#pragma unroll
  for (int r = 0; r < 4; r++) { m_run[r] = -1e30f; l_run[r] = 0.f; }

  const int q_row_out = qtile * 64 + w * 16 + (lane >> 4) * 4;   // + r

  const int ntiles = qtile + 1;
  for (int t = 0; t < ntiles; ++t) {
    const int kv0 = t * 64;
    __syncthreads();
    // stage K tile via global_load_lds, pre-swizzled source
#pragma unroll
    for (int i = 0; i < 2; i++) {
      int row = w * 8 + i * 32 + (lane >> 3);
      int col = ((lane & 7) * 8) ^ ((row & 7) << 3);
      gl2lds16(Kg + (size_t)(kv0 + row) * HD + col, Kl + (w * 8 + i * 32) * 128);
    }
    // stage V transposed: wave w owns d rows [w*16, w*16+16), key = lane
    {
      const unsigned short* vp = Vg + (size_t)(kv0 + lane) * HD + w * 16;
      bf8 v0 = *(const bf8*)(vp);
      bf8 v1 = *(const bf8*)(vp + 8);
#pragma unroll
      for (int e = 0; e < 8; e++) {
        int d = w * 16 + e;
        *(unsigned short*)(Vl + ((d * 128 + lane * 2) ^ ((d & 7) << 4))) = (unsigned short)v0[e];
      }
#pragma unroll
      for (int e = 0; e < 8; e++) {
        int d = w * 16 + 8 + e;
        *(unsigned short*)(Vl + ((d * 128 + lane * 2) ^ ((d & 7) << 4))) = (unsigned short)v1[e];
      }
    }
    __syncthreads();

    // S = Q K^T  (4 key-chunks of 16)
    f4 s[4] = {};
#pragma unroll
    for (int ks = 0; ks < 2; ks++) {
#pragma unroll
      for (int c = 0; c < 4; c++) {
        int krow = c * 16 + (lane & 15);
        bf8 kf = *(const bf8*)(Kl + krow * 128 + ((ks * 64 + (lane >> 4) * 16) ^ ((krow & 7) << 4)));
        s[c] = __builtin_amdgcn_mfma_f32_16x16x32_bf16(qfrag[ks], kf, s[c], 0, 0, 0);
      }
    }

    // scale + causal mask + online softmax; P -> LDS (bf16, swizzled)
#pragma unroll
    for (int r = 0; r < 4; r++) {
      int qr = q_row_out + r;
      float pv[4];
      float vmax = -1e30f;
#pragma unroll
      for (int c = 0; c < 4; c++) {
        int key = kv0 + c * 16 + (lane & 15);
        float sv = s[c][r] * 0.125f;
        if (key > qr) sv = -1e30f;
        pv[c] = sv;
        vmax = fmaxf(vmax, sv);
      }
      vmax = fmaxf(vmax, __shfl_xor(vmax, 1));
      vmax = fmaxf(vmax, __shfl_xor(vmax, 2));
      vmax = fmaxf(vmax, __shfl_xor(vmax, 4));
      vmax = fmaxf(vmax, __shfl_xor(vmax, 8));
      float mnew = fmaxf(m_run[r], vmax);
      float alpha = __expf(m_run[r] - mnew);
      m_run[r] = mnew;
      float rs = 0.f;
      int pr = (lane >> 4) * 4 + r;
#pragma unroll
      for (int c = 0; c < 4; c++) {
        float p = __expf(pv[c] - mnew);
        rs += p;
        int keyl = c * 16 + (lane & 15);
        *(unsigned short*)(Pl + ((pr * 128 + keyl * 2) ^ ((pr & 7) << 4))) = f2bf(p);
      }
      rs += __shfl_xor(rs, 1);
      rs += __shfl_xor(rs, 2);
      rs += __shfl_xor(rs, 4);
      rs += __shfl_xor(rs, 8);
      l_run[r] = l_run[r] * alpha + rs;
#pragma unroll
      for (int dc = 0; dc < 4; dc++) acc_o[dc][r] *= alpha;
    }

    // O += P V   (A = P from per-wave LDS, B = V^T from LDS)
#pragma unroll
    for (int ks = 0; ks < 2; ks++) {
      int q = lane & 15;
      bf8 pf = *(const bf8*)(Pl + q * 128 + ((ks * 64 + (lane >> 4) * 16) ^ ((q & 7) << 4)));
#pragma unroll
      for (int dc = 0; dc < 4; dc++) {
        int dr = dc * 16 + (lane & 15);
        bf8 vf = *(const bf8*)(Vl + dr * 128 + ((ks * 64 + (lane >> 4) * 16) ^ ((dr & 7) << 4)));
        acc_o[dc] = __builtin_amdgcn_mfma_f32_16x16x32_bf16(pf, vf, acc_o[dc], 0, 0, 0);
      }
    }
  }

  // normalize + store bf16 to [B][T][C]
  int b = bh >> 4, h = bh & 15;
  unsigned short* Og = Ob + (size_t)b * SEQ * EMBED;
#pragma unroll
  for (int r = 0; r < 4; r++) {
    int qr = q_row_out + r;
    float inv = 1.f / l_run[r];
#pragma unroll
    for (int dc = 0; dc < 4; dc++) {
      int cch = h * 64 + dc * 16 + (lane & 15);
      Og[(size_t)qr * EMBED + cch] = f2bf(acc_o[dc][r] * inv);
    }
  }
}

extern "C" void kernel_launch(void* const* d_in, const int* in_sizes, int n_in,
                              void* d_out, int out_size, void* d_ws, size_t ws_size,
                              hipStream_t stream) {
  const float* x    = (const float*)d_in[0];
  const float* Wqkv = (const float*)d_in[1];
  const float* bqkv = (const float*)d_in[2];
  const float* Wout = (const float*)d_in[3];
  const float* bout = (const float*)d_in[4];
  float* out = (float*)d_out;

  char* ws = (char*)d_ws;
  unsigned short* xb    = (unsigned short*)ws;                          // 8 MB  [4096][1024]
  unsigned short* wqkvT = (unsigned short*)(ws + (size_t)8  * 1048576); // 6 MB  [3072][1024]
  unsigned short* woutT = (unsigned short*)(ws + (size_t)14 * 1048576); // 2 MB  [1024][1024]
  unsigned short* qkv   = (unsigned short*)(ws + (size_t)16 * 1048576); // 24 MB [3][B][H][T][D]
  unsigned short* obuf  = (unsigned short*)(ws + (size_t)40 * 1048576); // 8 MB  [B][T][C]

  conv_bf16<<<4096, 256, 0, stream>>>(x, xb);
  transp_bf16<<<dim3(48, 16), 256, 0, stream>>>(Wqkv, wqkvT, 1024, 3072);
  transp_bf16<<<dim3(16, 16), 256, 0, stream>>>(Wout, woutT, 1024, 1024);

  gemm_bt<<<dim3(24, 32), 256, 0, stream>>>(xb, wqkvT, bqkv, qkv, MTOK, 3 * EMBED, EMBED, 0);

  const unsigned short* Qb = qkv;
  const unsigned short* Kb = qkv + (size_t)32 * SEQ * HD;
  const unsigned short* Vb = qkv + (size_t)2 * 32 * SEQ * HD;
  attn_kernel<<<dim3(SEQ / 64, 32), 256, 0, stream>>>(Qb, Kb, Vb, obuf);

  gemm_bt<<<dim3(8, 32), 256, 0, stream>>>(obuf, woutT, bout, out, MTOK, EMBED, EMBED, 1);
}

// Round 2
// 159.596 us; speedup vs baseline: 1.3559x; 1.3559x over previous
//
#include <hip/hip_runtime.h>
#include <stdint.h>

#define EMBED 1024
#define NH 16
#define HD 64
#define BATCH 2
#define SEQ 2048
#define MTOK (BATCH*SEQ)   // 4096

using bf8 = __attribute__((ext_vector_type(8))) short;   // 8 bf16 = one MFMA A/B frag
using f4  = __attribute__((ext_vector_type(4))) float;   // MFMA C/D frag
using u16x4 = __attribute__((ext_vector_type(4))) unsigned short;

__device__ __forceinline__ unsigned short f2bf(float f) {
  union { float f; uint32_t u; } v; v.f = f;
  uint32_t u = v.u;
  return (unsigned short)((u + 0x7FFFu + ((u >> 16) & 1u)) >> 16);  // RNE
}

__device__ __forceinline__ void gl2lds16(const void* g, void* l) {
  __builtin_amdgcn_global_load_lds(
      (const __attribute__((address_space(1))) void*)g,
      (__attribute__((address_space(3))) void*)l, 16, 0, 0);
}

// ---------------- prep: fp32 -> bf16 ----------------
__global__ __launch_bounds__(256) void conv_bf16(const float* __restrict__ x,
                                                 unsigned short* __restrict__ y) {
  int i = (blockIdx.x * 256 + threadIdx.x) * 4;
  float4 v = *(const float4*)(x + i);
  u16x4 o;
  o[0] = f2bf(v.x); o[1] = f2bf(v.y); o[2] = f2bf(v.z); o[3] = f2bf(v.w);
  *(u16x4*)(y + i) = o;
}

// ---------------- prep: transpose fp32 [K][N] -> bf16 [N][K] ----------------
__global__ __launch_bounds__(256) void transp_bf16(const float* __restrict__ W,
                                                   unsigned short* __restrict__ Wt,
                                                   int K, int N) {
  __shared__ float tl[64][65];
  int k0 = blockIdx.y * 64, n0 = blockIdx.x * 64;
  int tr = threadIdx.x >> 6, tc = threadIdx.x & 63;
#pragma unroll
  for (int i = 0; i < 16; i++) {
    int r = tr + i * 4;
    tl[r][tc] = W[(size_t)(k0 + r) * N + n0 + tc];
  }
  __syncthreads();
#pragma unroll
  for (int i = 0; i < 16; i++) {
    int r = tr + i * 4;
    Wt[(size_t)(n0 + r) * K + k0 + tc] = f2bf(tl[tc][r]);
  }
}

// ---------------- transpose V bf16 [t][d] -> Vt [d][t] per bh ----------------
__global__ __launch_bounds__(256) void transp_v(const unsigned short* __restrict__ V,
                                                unsigned short* __restrict__ Vt) {
  __shared__ unsigned short tl[64][65];
  int bh = blockIdx.y, t0 = blockIdx.x * 64;
  const unsigned short* Vg = V + (size_t)bh * SEQ * HD;
  unsigned short* Og = Vt + (size_t)bh * SEQ * HD;
  int lane = threadIdx.x & 63, quad = threadIdx.x >> 6;
#pragma unroll
  for (int i = 0; i < 16; i++) {
    int r = quad * 16 + i;
    tl[r][lane] = Vg[(size_t)(t0 + r) * HD + lane];
  }
  __syncthreads();
#pragma unroll
  for (int i = 0; i < 16; i++) {
    int d = quad * 16 + i;
    Og[(size_t)d * SEQ + t0 + lane] = tl[lane][d];
  }
}

// ---------------- bf16 GEMM: C[M][N] = A[M][K] * Bt[N][K]^T + bias ----------------
// mode 0: scatter bf16 into qkv [3][B][H][T][D] (Q pre-scaled by 1/sqrt(D));
// mode 1: fp32 row-major out
__global__ __launch_bounds__(256) void gemm_bt(const unsigned short* __restrict__ A,
                                               const unsigned short* __restrict__ Bt,
                                               const float* __restrict__ bias,
                                               void* __restrict__ Cout,
                                               int M, int N, int K, int mode) {
  const int tid = threadIdx.x;
  const int w = tid >> 6, lane = tid & 63;
  const int wm = w >> 1, wn = w & 1;                 // 2x2 waves, each 64x64
  const int m0 = blockIdx.y * 128, n0 = blockIdx.x * 128;

  __shared__ char smem[32768];
  char* Al = smem;              // [128 m][64 k] bf16, XOR-swizzled rows
  char* Bl = smem + 16384;      // [128 n][64 k] bf16, XOR-swizzled rows

  f4 acc[4][4] = {};

  for (int k0 = 0; k0 < K; k0 += 64) {
    __syncthreads();
#pragma unroll
    for (int i = 0; i < 4; i++) {
      int row = w * 8 + i * 32 + (lane >> 3);
      int col = ((lane & 7) * 8) ^ ((row & 7) << 3);   // pre-swizzled global source
      gl2lds16(A  + (size_t)(m0 + row) * K + k0 + col, Al + (w * 8 + i * 32) * 128);
      gl2lds16(Bt + (size_t)(n0 + row) * K + k0 + col, Bl + (w * 8 + i * 32) * 128);
    }
    __syncthreads();
#pragma unroll
    for (int ks = 0; ks < 2; ks++) {
      bf8 af[4], bfr[4];
#pragma unroll
      for (int mt = 0; mt < 4; mt++) {
        int rr = wm * 64 + mt * 16 + (lane & 15);
        af[mt] = *(const bf8*)(Al + rr * 128 + ((ks * 64 + (lane >> 4) * 16) ^ ((rr & 7) << 4)));
      }
#pragma unroll
      for (int nt = 0; nt < 4; nt++) {
        int rr = wn * 64 + nt * 16 + (lane & 15);
        bfr[nt] = *(const bf8*)(Bl + rr * 128 + ((ks * 64 + (lane >> 4) * 16) ^ ((rr & 7) << 4)));
      }
#pragma unroll
      for (int mt = 0; mt < 4; mt++)
#pragma unroll
        for (int nt = 0; nt < 4; nt++)
          acc[mt][nt] = __builtin_amdgcn_mfma_f32_16x16x32_bf16(af[mt], bfr[nt], acc[mt][nt], 0, 0, 0);
    }
  }

  if (mode == 0) {
    unsigned short* Q = (unsigned short*)Cout;   // [3][B][H][T][D]
#pragma unroll
    for (int nt = 0; nt < 4; nt++) {
      int n = n0 + wn * 64 + nt * 16 + (lane & 15);
      float bv = bias[n];
      int region = n >> 10, c = n & 1023, h = c >> 6, d = c & 63;
      float sc = (region == 0) ? 0.125f : 1.0f;   // fold 1/sqrt(64) into Q
#pragma unroll
      for (int mt = 0; mt < 4; mt++) {
#pragma unroll
        for (int r = 0; r < 4; r++) {
          int m = m0 + wm * 64 + mt * 16 + (lane >> 4) * 4 + r;
          int b = m >> 11, t = m & 2047;
          size_t off = ((((size_t)region * 2 + b) * 16 + h) * 2048 + t) * 64 + d;
          Q[off] = f2bf((acc[mt][nt][r] + bv) * sc);
        }
      }
    }
  } else {
    float* O = (float*)Cout;
#pragma unroll
    for (int mt = 0; mt < 4; mt++) {
#pragma unroll
      for (int r = 0; r < 4; r++) {
        int m = m0 + wm * 64 + mt * 16 + (lane >> 4) * 4 + r;
#pragma unroll
        for (int nt = 0; nt < 4; nt++) {
          int n = n0 + wn * 64 + nt * 16 + (lane & 15);
          O[(size_t)m * N + n] = acc[mt][nt][r] + bias[n];
        }
      }
    }
  }
}

// ---------------- causal flash attention v2 ----------------
// swapped QK^T (lane owns one q-row's P values), V pre-transposed, K/Vt
// double-buffered via global_load_lds. grid (qtile desc, bh), 4 waves.
__global__ __launch_bounds__(256) void attn2(const unsigned short* __restrict__ Qb,
                                             const unsigned short* __restrict__ Kb,
                                             const unsigned short* __restrict__ Vtb,
                                             unsigned short* __restrict__ Ob) {
  const int qtile = (SEQ / 64 - 1) - blockIdx.x;   // heavy blocks first
  const int bh = blockIdx.y;
  const int tid = threadIdx.x;
  const int w = tid >> 6, lane = tid & 63;
  const int g = lane >> 4, ql = lane & 15;

  __shared__ char smem[40960];                     // K[2]*8K + Vt[2]*8K + P 4*2K
  char* Pl = smem + 32768 + w * 2048;              // per-wave [16 q][64 key] swizzled

  const unsigned short* Qg  = Qb  + (size_t)bh * SEQ * HD;
  const unsigned short* Kg  = Kb  + (size_t)bh * SEQ * HD;
  const unsigned short* Vtg = Vtb + (size_t)bh * SEQ * HD;  // [64 d][2048 t]

  const int qrow = qtile * 64 + w * 16 + ql;       // this lane's q-row
  bf8 qf0 = *(const bf8*)(Qg + (size_t)qrow * HD + g * 8);
  bf8 qf1 = *(const bf8*)(Qg + (size_t)qrow * HD + 32 + g * 8);

  f4 acc[4] = {};                                   // O rows g*4+r, col d = dc*16+ql
  float m_run = -1e30f, l_run = 0.f;
  const int ntiles = qtile + 1;

  auto STAGE = [&](char* kd, char* vd, int t) {
    int kv0 = t * 64;
#pragma unroll
    for (int i = 0; i < 2; i++) {
      int row = w * 8 + i * 32 + (lane >> 3);
      int col = ((lane & 7) * 8) ^ ((row & 7) << 3);   // pre-swizzled source
      gl2lds16(Kg + (size_t)(kv0 + row) * HD + col,  kd + (w * 8 + i * 32) * 128);
      gl2lds16(Vtg + (size_t)row * SEQ + kv0 + col,  vd + (w * 8 + i * 32) * 128);
    }
  };

  STAGE(smem, smem + 16384, 0);
  __syncthreads();

  for (int t = 0; t < ntiles; t++) {
    char* kb = smem + (t & 1) * 8192;
    char* vb = smem + 16384 + (t & 1) * 8192;
    if (t + 1 < ntiles)   // prefetch next tile into other buffer (overlaps compute)
      STAGE(smem + ((t + 1) & 1) * 8192, smem + 16384 + ((t + 1) & 1) * 8192, t + 1);

    // S^T = K Q^T : s[c] -> key = kv0 + c*16 + g*4 + r, q = ql (lane-local row!)
    f4 s[4] = {};
    __builtin_amdgcn_s_setprio(1);
#pragma unroll
    for (int ks = 0; ks < 2; ks++) {
      bf8 qf = ks ? qf1 : qf0;
#pragma unroll
      for (int c = 0; c < 4; c++) {
        int krow = c * 16 + ql;
        bf8 kf = *(const bf8*)(kb + krow * 128 + ((ks * 64 + g * 16) ^ ((krow & 7) << 4)));
        s[c] = __builtin_amdgcn_mfma_f32_16x16x32_bf16(kf, qf, s[c], 0, 0, 0);
      }
    }
    __builtin_amdgcn_s_setprio(0);

    if (t == ntiles - 1) {                         // only diagonal tile needs mask
      int kv0 = t * 64;
#pragma unroll
      for (int c = 0; c < 4; c++)
#pragma unroll
        for (int r = 0; r < 4; r++) {
          int key = kv0 + c * 16 + g * 4 + r;
          if (key > qrow) s[c][r] = -1e30f;
        }
    }

    float vmax = -1e30f;
#pragma unroll
    for (int c = 0; c < 4; c++)
#pragma unroll
      for (int r = 0; r < 4; r++) vmax = fmaxf(vmax, s[c][r]);
    vmax = fmaxf(vmax, __shfl_xor(vmax, 16));
    vmax = fmaxf(vmax, __shfl_xor(vmax, 32));
    float mnew = fmaxf(m_run, vmax);
    float alpha = __expf(m_run - mnew);
    m_run = mnew;

    float rs = 0.f;
#pragma unroll
    for (int c = 0; c < 4; c++) {                  // exp + packed b64 P-write
      u16x4 pk;
#pragma unroll
      for (int r = 0; r < 4; r++) {
        float p = __expf(s[c][r] - mnew);
        rs += p;
        pk[r] = f2bf(p);
      }
      *(u16x4*)(Pl + ((ql * 128 + c * 32 + g * 8) ^ ((ql & 7) << 4))) = pk;
    }
    rs += __shfl_xor(rs, 16);
    rs += __shfl_xor(rs, 32);
    l_run = l_run * alpha + rs;

    // rescale O: rows q' = g*4+r, alpha lives in lane q'
    float af0 = __shfl(alpha, g * 4 + 0);
    float af1 = __shfl(alpha, g * 4 + 1);
    float af2 = __shfl(alpha, g * 4 + 2);
    float af3 = __shfl(alpha, g * 4 + 3);
#pragma unroll
    for (int dc = 0; dc < 4; dc++) {
      acc[dc][0] *= af0; acc[dc][1] *= af1; acc[dc][2] *= af2; acc[dc][3] *= af3;
    }

    // O += P V  (A = P[q][key] from per-wave LDS, B = V^T[d][key])
    __builtin_amdgcn_s_setprio(1);
#pragma unroll
    for (int ks = 0; ks < 2; ks++) {
      bf8 pf = *(const bf8*)(Pl + ql * 128 + ((ks * 64 + g * 16) ^ ((ql & 7) << 4)));
#pragma unroll
      for (int dc = 0; dc < 4; dc++) {
        int dr = dc * 16 + ql;
        bf8 vf = *(const bf8*)(vb + dr * 128 + ((ks * 64 + g * 16) ^ ((dr & 7) << 4)));
        acc[dc] = __builtin_amdgcn_mfma_f32_16x16x32_bf16(pf, vf, acc[dc], 0, 0, 0);
      }
    }
    __builtin_amdgcn_s_setprio(0);
    __syncthreads();   // drains prefetch vmcnt + guards buffer swap
  }

  float linv0 = 1.f / __shfl(l_run, g * 4 + 0);
  float linv1 = 1.f / __shfl(l_run, g * 4 + 1);
  float linv2 = 1.f / __shfl(l_run, g * 4 + 2);
  float linv3 = 1.f / __shfl(l_run, g * 4 + 3);

  int b = bh >> 4, h = bh & 15;
  unsigned short* Og = Ob + (size_t)b * SEQ * EMBED;
  int qbase = qtile * 64 + w * 16 + g * 4;
#pragma unroll
  for (int dc = 0; dc < 4; dc++) {
    int cc = h * 64 + dc * 16 + ql;
    Og[(size_t)(qbase + 0) * EMBED + cc] = f2bf(acc[dc][0] * linv0);
    Og[(size_t)(qbase + 1) * EMBED + cc] = f2bf(acc[dc][1] * linv1);
    Og[(size_t)(qbase + 2) * EMBED + cc] = f2bf(acc[dc][2] * linv2);
    Og[(size_t)(qbase + 3) * EMBED + cc] = f2bf(acc[dc][3] * linv3);
  }
}

extern "C" void kernel_launch(void* const* d_in, const int* in_sizes, int n_in,
                              void* d_out, int out_size, void* d_ws, size_t ws_size,
                              hipStream_t stream) {
  const float* x    = (const float*)d_in[0];
  const float* Wqkv = (const float*)d_in[1];
  const float* bqkv = (const float*)d_in[2];
  const float* Wout = (const float*)d_in[3];
  const float* bout = (const float*)d_in[4];
  float* out = (float*)d_out;

  char* ws = (char*)d_ws;
  unsigned short* xb    = (unsigned short*)ws;                          // 8 MB (dead after QKV GEMM)
  unsigned short* vT    = (unsigned short*)ws;                          // 8 MB, overlays xb
  unsigned short* wqkvT = (unsigned short*)(ws + (size_t)8  * 1048576); // 6 MB
  unsigned short* woutT = (unsigned short*)(ws + (size_t)14 * 1048576); // 2 MB
  unsigned short* qkv   = (unsigned short*)(ws + (size_t)16 * 1048576); // 24 MB [3][B][H][T][D]
  unsigned short* obuf  = (unsigned short*)(ws + (size_t)40 * 1048576); // 8 MB  [B][T][C]

  conv_bf16<<<4096, 256, 0, stream>>>(x, xb);
  transp_bf16<<<dim3(48, 16), 256, 0, stream>>>(Wqkv, wqkvT, 1024, 3072);
  transp_bf16<<<dim3(16, 16), 256, 0, stream>>>(Wout, woutT, 1024, 1024);

  gemm_bt<<<dim3(24, 32), 256, 0, stream>>>(xb, wqkvT, bqkv, qkv, MTOK, 3 * EMBED, EMBED, 0);

  const unsigned short* Qb = qkv;
  const unsigned short* Kb = qkv + (size_t)32 * SEQ * HD;
  const unsigned short* Vb = qkv + (size_t)2 * 32 * SEQ * HD;
  transp_v<<<dim3(32, 32), 256, 0, stream>>>(Vb, vT);

  attn2<<<dim3(SEQ / 64, 32), 256, 0, stream>>>(Qb, Kb, vT, obuf);

  gemm_bt<<<dim3(8, 32), 256, 0, stream>>>(obuf, woutT, bout, out, MTOK, EMBED, EMBED, 1);
}

// Round 3
// 140.646 us; speedup vs baseline: 1.5386x; 1.1347x over previous
//
#include <hip/hip_runtime.h>
#include <hip/hip_bf16.h>
#include <stdint.h>

#define EMBED 1024
#define NH 16
#define HD 64
#define BATCH 2
#define SEQ 2048
#define MTOK (BATCH*SEQ)   // 4096

using bf8 = __attribute__((ext_vector_type(8))) short;   // 8 bf16 = one MFMA A/B frag
using f4  = __attribute__((ext_vector_type(4))) float;   // MFMA C/D frag
using u16x4 = __attribute__((ext_vector_type(4))) unsigned short;

__device__ __forceinline__ uint32_t pk_bf16(float a, float b) {
  __hip_bfloat162 h = __float22bfloat162_rn(float2{a, b});
  union { __hip_bfloat162 h; uint32_t u; } c; c.h = h; return c.u;
}
__device__ __forceinline__ unsigned short bfbits(float f) {
  __hip_bfloat16 h = __float2bfloat16(f);
  union { __hip_bfloat16 h; unsigned short u; } c; c.h = h; return c.u;
}
__device__ __forceinline__ float fexp2(float x) {
#if __has_builtin(__builtin_amdgcn_exp2f)
  return __builtin_amdgcn_exp2f(x);
#else
  return exp2f(x);
#endif
}

__device__ __forceinline__ void gl2lds16(const void* g, void* l) {
  __builtin_amdgcn_global_load_lds(
      (const __attribute__((address_space(1))) void*)g,
      (__attribute__((address_space(3))) void*)l, 16, 0, 0);
}

// ---------------- prep: fp32 -> bf16 ----------------
__global__ __launch_bounds__(256) void conv_bf16(const float* __restrict__ x,
                                                 unsigned short* __restrict__ y) {
  int i = (blockIdx.x * 256 + threadIdx.x) * 4;
  float4 v = *(const float4*)(x + i);
  uint2 o;
  o.x = pk_bf16(v.x, v.y);
  o.y = pk_bf16(v.z, v.w);
  *(uint2*)(y + i) = o;
}

// ---------------- prep: transpose fp32 [K][N] -> bf16 [N][K] ----------------
__global__ __launch_bounds__(256) void transp_bf16(const float* __restrict__ W,
                                                   unsigned short* __restrict__ Wt,
                                                   int K, int N) {
  __shared__ float tl[64][65];
  int k0 = blockIdx.y * 64, n0 = blockIdx.x * 64;
  int tr = threadIdx.x >> 6, tc = threadIdx.x & 63;
#pragma unroll
  for (int i = 0; i < 16; i++) {
    int r = tr + i * 4;
    tl[r][tc] = W[(size_t)(k0 + r) * N + n0 + tc];
  }
  __syncthreads();
#pragma unroll
  for (int i = 0; i < 16; i++) {
    int r = tr + i * 4;
    Wt[(size_t)(n0 + r) * K + k0 + tc] = bfbits(tl[tc][r]);
  }
}

// ---------------- bf16 GEMM: C[M][N] = A[M][K] * Bt[N][K]^T + bias ----------------
// MODE 0 (BN=128): scatter bf16; Q (scaled by 0.125*log2e) and K -> Oq [2][B][H][T][D],
//                  V -> Ov transposed [B*H][D][T].
// MODE 1: fp32 row-major Of.
template<int BN, int MODE>
__global__ __launch_bounds__(256) void gemm_bt(const unsigned short* __restrict__ A,
                                               const unsigned short* __restrict__ Bt,
                                               const float* __restrict__ bias,
                                               unsigned short* __restrict__ Oq,
                                               unsigned short* __restrict__ Ov,
                                               float* __restrict__ Of,
                                               int M, int N, int K) {
  constexpr int MT = (BN == 128) ? 4 : 2;
  const int tid = threadIdx.x;
  const int w = tid >> 6, lane = tid & 63;
  const int wm = (BN == 128) ? (w >> 1) : w;
  const int wn = (BN == 128) ? (w & 1) : 0;
  const int m0 = blockIdx.y * 128, n0 = blockIdx.x * BN;

  __shared__ char smem[16384 + BN * 128];
  char* Al = smem;              // [128 m][64 k] bf16, XOR-swizzled rows
  char* Bl = smem + 16384;      // [BN n][64 k]

  f4 acc[MT][4] = {};

  for (int k0 = 0; k0 < K; k0 += 64) {
    __syncthreads();
#pragma unroll
    for (int i = 0; i < 4; i++) {
      int row = w * 8 + i * 32 + (lane >> 3);
      int col = ((lane & 7) * 8) ^ ((row & 7) << 3);   // pre-swizzled global source
      gl2lds16(A + (size_t)(m0 + row) * K + k0 + col, Al + (w * 8 + i * 32) * 128);
    }
#pragma unroll
    for (int i = 0; i < BN / 32; i++) {
      int row = w * 8 + i * 32 + (lane >> 3);
      int col = ((lane & 7) * 8) ^ ((row & 7) << 3);
      gl2lds16(Bt + (size_t)(n0 + row) * K + k0 + col, Bl + (w * 8 + i * 32) * 128);
    }
    __syncthreads();
#pragma unroll
    for (int ks = 0; ks < 2; ks++) {
      bf8 af[MT], bfr[4];
#pragma unroll
      for (int mt = 0; mt < MT; mt++) {
        int rr = wm * (MT * 16) + mt * 16 + (lane & 15);
        af[mt] = *(const bf8*)(Al + rr * 128 + ((ks * 64 + (lane >> 4) * 16) ^ ((rr & 7) << 4)));
      }
#pragma unroll
      for (int nt = 0; nt < 4; nt++) {
        int rr = wn * 64 + nt * 16 + (lane & 15);
        bfr[nt] = *(const bf8*)(Bl + rr * 128 + ((ks * 64 + (lane >> 4) * 16) ^ ((rr & 7) << 4)));
      }
#pragma unroll
      for (int mt = 0; mt < MT; mt++)
#pragma unroll
        for (int nt = 0; nt < 4; nt++)
          acc[mt][nt] = __builtin_amdgcn_mfma_f32_16x16x32_bf16(af[mt], bfr[nt], acc[mt][nt], 0, 0, 0);
    }
  }

  if (MODE == 0) {
#pragma unroll
    for (int nt = 0; nt < 4; nt++) {
      int n = n0 + wn * 64 + nt * 16 + (lane & 15);
      float bv = bias[n];
      int region = n >> 10, c = n & 1023, h = c >> 6, d = c & 63;
      float sc = (region == 0) ? 0.180336880f : 1.0f;  // 1/8 * log2(e) folded into Q
#pragma unroll
      for (int mt = 0; mt < MT; mt++) {
#pragma unroll
        for (int r = 0; r < 4; r++) {
          int m = m0 + wm * (MT * 16) + mt * 16 + (lane >> 4) * 4 + r;
          int b = m >> 11, t = m & 2047;
          unsigned short val = bfbits((acc[mt][nt][r] + bv) * sc);
          if (region < 2) {
            size_t off = ((((size_t)region * 2 + b) * 16 + h) * 2048 + t) * 64 + d;
            Oq[off] = val;
          } else {
            size_t off = (((size_t)b * 16 + h) * 64 + d) * 2048 + t;   // V transposed
            Ov[off] = val;
          }
        }
      }
    }
  } else {
#pragma unroll
    for (int mt = 0; mt < MT; mt++) {
#pragma unroll
      for (int r = 0; r < 4; r++) {
        int m = m0 + wm * (MT * 16) + mt * 16 + (lane >> 4) * 4 + r;
#pragma unroll
        for (int nt = 0; nt < 4; nt++) {
          int n = n0 + wn * 64 + nt * 16 + (lane & 15);
          Of[(size_t)m * N + n] = acc[mt][nt][r] + bias[n];
        }
      }
    }
  }
}

// ---------------- causal flash attention v3 ----------------
// 2 waves x 32 q-rows (two 16-row groups per wave -> ILP on the softmax chain).
// Swapped QK^T, exp2 domain, defer-max (THR=8), per-lane partial l, K/Vt
// double-buffered via global_load_lds. grid (qtile desc, bh).
__global__ __launch_bounds__(128) void attn3(const unsigned short* __restrict__ Qb,
                                             const unsigned short* __restrict__ Kb,
                                             const unsigned short* __restrict__ Vtb,
                                             unsigned short* __restrict__ Ob) {
  const int qt = (SEQ / 64 - 1) - blockIdx.x;   // heavy blocks first
  const int bh = blockIdx.y;
  const int tid = threadIdx.x;
  const int w = tid >> 6, lane = tid & 63;
  const int g = lane >> 4, ql = lane & 15;

  __shared__ char smem[40960];                  // K[2]*8K + Vt[2]*8K + P 2*4K
  char* Pl = smem + 32768 + w * 4096;           // per-wave [32 q][64 key] swizzled

  const unsigned short* Qg  = Qb  + (size_t)bh * SEQ * HD;
  const unsigned short* Kg  = Kb  + (size_t)bh * SEQ * HD;
  const unsigned short* Vtg = Vtb + (size_t)bh * SEQ * HD;  // [64 d][2048 t]

  const int qr0 = qt * 64 + w * 32 + ql;        // group-0 q-row of this lane
  const int qr1 = qr0 + 16;                     // group-1
  bf8 qf[2][2];
  qf[0][0] = *(const bf8*)(Qg + (size_t)qr0 * HD + g * 8);
  qf[0][1] = *(const bf8*)(Qg + (size_t)qr0 * HD + 32 + g * 8);
  qf[1][0] = *(const bf8*)(Qg + (size_t)qr1 * HD + g * 8);
  qf[1][1] = *(const bf8*)(Qg + (size_t)qr1 * HD + 32 + g * 8);

  f4 acc[2][4] = {};                            // [group][d-chunk]
  float m0 = -1e30f, m1 = -1e30f;
  float l0 = 0.f, l1 = 0.f;                     // per-lane partial row-sums
  const int ntiles = qt + 1;

  auto STAGE = [&](int buf, int t) {
    int kv0 = t * 64;
#pragma unroll
    for (int i = 0; i < 4; i++) {
      int row = i * 16 + w * 8 + (lane >> 3);
      int col = ((lane & 7) * 8) ^ ((row & 7) << 3);   // pre-swizzled source
      gl2lds16(Kg + (size_t)(kv0 + row) * HD + col,  smem + buf * 8192 + (i * 16 + w * 8) * 128);
      gl2lds16(Vtg + (size_t)row * SEQ + kv0 + col,  smem + 16384 + buf * 8192 + (i * 16 + w * 8) * 128);
    }
  };

  STAGE(0, 0);
  __syncthreads();

  for (int t = 0; t < ntiles; t++) {
    const char* kb = smem + (t & 1) * 8192;
    const char* vb = smem + 16384 + (t & 1) * 8192;
    if (t + 1 < ntiles)
      STAGE((t + 1) & 1, t + 1);                // prefetch overlaps compute

    // S^T = K Q^T : key = kv0 + c*16 + g*4 + r, q = ql (lane-local row)
    f4 s0[4] = {}, s1[4] = {};
    __builtin_amdgcn_s_setprio(1);
#pragma unroll
    for (int ks = 0; ks < 2; ks++) {
#pragma unroll
      for (int c = 0; c < 4; c++) {
        int krow = c * 16 + ql;
        bf8 kf = *(const bf8*)(kb + krow * 128 + ((ks * 64 + g * 16) ^ ((krow & 7) << 4)));
        s0[c] = __builtin_amdgcn_mfma_f32_16x16x32_bf16(kf, qf[0][ks], s0[c], 0, 0, 0);
        s1[c] = __builtin_amdgcn_mfma_f32_16x16x32_bf16(kf, qf[1][ks], s1[c], 0, 0, 0);
      }
    }
    __builtin_amdgcn_s_setprio(0);

    if (t == ntiles - 1) {                      // only diagonal tile needs mask
      int kv0 = t * 64;
#pragma unroll
      for (int c = 0; c < 4; c++)
#pragma unroll
        for (int r = 0; r < 4; r++) {
          int key = kv0 + c * 16 + g * 4 + r;
          if (key > qr0) s0[c][r] = -1e30f;
          if (key > qr1) s1[c][r] = -1e30f;
        }
    }

    float v0 = -1e30f, v1 = -1e30f;
#pragma unroll
    for (int c = 0; c < 4; c++)
#pragma unroll
      for (int r = 0; r < 4; r++) {
        v0 = fmaxf(v0, s0[c][r]);
        v1 = fmaxf(v1, s1[c][r]);
      }
    v0 = fmaxf(v0, __shfl_xor(v0, 16)); v0 = fmaxf(v0, __shfl_xor(v0, 32));
    v1 = fmaxf(v1, __shfl_xor(v1, 16)); v1 = fmaxf(v1, __shfl_xor(v1, 32));

    // defer-max: rescale only when a row's max grew past THR=8 (log2 units)
    if (__any(v0 > m0 + 8.f) || __any(v1 > m1 + 8.f)) {
      float n0 = fmaxf(m0, v0), n1 = fmaxf(m1, v1);
      float a0 = fexp2(m0 - n0), a1 = fexp2(m1 - n1);
      m0 = n0; m1 = n1;
      l0 *= a0; l1 *= a1;
      float b0[4], b1[4];
#pragma unroll
      for (int r = 0; r < 4; r++) { b0[r] = __shfl(a0, g * 4 + r); b1[r] = __shfl(a1, g * 4 + r); }
#pragma unroll
      for (int dc = 0; dc < 4; dc++)
#pragma unroll
        for (int r = 0; r < 4; r++) { acc[0][dc][r] *= b0[r]; acc[1][dc][r] *= b1[r]; }
    }

    // P = exp2(S - m), packed bf16 -> per-wave LDS
#pragma unroll
    for (int c = 0; c < 4; c++) {
      float p00 = fexp2(s0[c][0] - m0), p01 = fexp2(s0[c][1] - m0);
      float p02 = fexp2(s0[c][2] - m0), p03 = fexp2(s0[c][3] - m0);
      float p10 = fexp2(s1[c][0] - m1), p11 = fexp2(s1[c][1] - m1);
      float p12 = fexp2(s1[c][2] - m1), p13 = fexp2(s1[c][3] - m1);
      l0 += (p00 + p01) + (p02 + p03);
      l1 += (p10 + p11) + (p12 + p13);
      uint2 w0, w1;
      w0.x = pk_bf16(p00, p01); w0.y = pk_bf16(p02, p03);
      w1.x = pk_bf16(p10, p11); w1.y = pk_bf16(p12, p13);
      *(uint2*)(Pl + ((ql * 128 + c * 32 + g * 8) ^ ((ql & 7) << 4))) = w0;
      *(uint2*)(Pl + (((16 + ql) * 128 + c * 32 + g * 8) ^ ((ql & 7) << 4))) = w1;
    }

    // O += P V   (A = P[q][key], B = V^T[d][key]); vf reused across both groups
    __builtin_amdgcn_s_setprio(1);
#pragma unroll
    for (int ks = 0; ks < 2; ks++) {
      bf8 pf0 = *(const bf8*)(Pl + ql * 128 + ((ks * 64 + g * 16) ^ ((ql & 7) << 4)));
      bf8 pf1 = *(const bf8*)(Pl + (16 + ql) * 128 + ((ks * 64 + g * 16) ^ ((ql & 7) << 4)));
#pragma unroll
      for (int dc = 0; dc < 4; dc++) {
        int dr = dc * 16 + ql;
        bf8 vf = *(const bf8*)(vb + dr * 128 + ((ks * 64 + g * 16) ^ ((dr & 7) << 4)));
        acc[0][dc] = __builtin_amdgcn_mfma_f32_16x16x32_bf16(pf0, vf, acc[0][dc], 0, 0, 0);
        acc[1][dc] = __builtin_amdgcn_mfma_f32_16x16x32_bf16(pf1, vf, acc[1][dc], 0, 0, 0);
      }
    }
    __builtin_amdgcn_s_setprio(0);
    __syncthreads();   // drains prefetch + guards buffer swap
  }

  // finalize: reduce partial l across g-lanes, normalize, store
  l0 += __shfl_xor(l0, 16); l0 += __shfl_xor(l0, 32);
  l1 += __shfl_xor(l1, 16); l1 += __shfl_xor(l1, 32);
  float li0[4], li1[4];
#pragma unroll
  for (int r = 0; r < 4; r++) {
    li0[r] = 1.f / __shfl(l0, g * 4 + r);
    li1[r] = 1.f / __shfl(l1, g * 4 + r);
  }

  int b = bh >> 4, h = bh & 15;
  unsigned short* Og = Ob + (size_t)b * SEQ * EMBED;
  int qb0 = qt * 64 + w * 32 + g * 4;
#pragma unroll
  for (int dc = 0; dc < 4; dc++) {
    int cc = h * 64 + dc * 16 + ql;
#pragma unroll
    for (int r = 0; r < 4; r++) {
      Og[(size_t)(qb0 + r) * EMBED + cc]      = bfbits(acc[0][dc][r] * li0[r]);
      Og[(size_t)(qb0 + 16 + r) * EMBED + cc] = bfbits(acc[1][dc][r] * li1[r]);
    }
  }
}

extern "C" void kernel_launch(void* const* d_in, const int* in_sizes, int n_in,
                              void* d_out, int out_size, void* d_ws, size_t ws_size,
                              hipStream_t stream) {
  const float* x    = (const float*)d_in[0];
  const float* Wqkv = (const float*)d_in[1];
  const float* bqkv = (const float*)d_in[2];
  const float* Wout = (const float*)d_in[3];
  const float* bout = (const float*)d_in[4];
  float* out = (float*)d_out;

  char* ws = (char*)d_ws;
  unsigned short* xb    = (unsigned short*)ws;                          // 8 MB
  unsigned short* wqkvT = (unsigned short*)(ws + (size_t)8  * 1048576); // 6 MB
  unsigned short* woutT = (unsigned short*)(ws + (size_t)14 * 1048576); // 2 MB
  unsigned short* qk    = (unsigned short*)(ws + (size_t)16 * 1048576); // 16 MB [2][B][H][T][D]
  unsigned short* vT    = (unsigned short*)(ws + (size_t)32 * 1048576); // 8 MB  [B*H][D][T]
  unsigned short* obuf  = (unsigned short*)(ws + (size_t)40 * 1048576); // 8 MB  [B][T][C]

  conv_bf16<<<4096, 256, 0, stream>>>(x, xb);
  transp_bf16<<<dim3(48, 16), 256, 0, stream>>>(Wqkv, wqkvT, 1024, 3072);
  transp_bf16<<<dim3(16, 16), 256, 0, stream>>>(Wout, woutT, 1024, 1024);

  gemm_bt<128, 0><<<dim3(24, 32), 256, 0, stream>>>(xb, wqkvT, bqkv, qk, vT, nullptr,
                                                    MTOK, 3 * EMBED, EMBED);

  const unsigned short* Qb = qk;
  const unsigned short* Kb = qk + (size_t)BATCH * NH * SEQ * HD;
  attn3<<<dim3(SEQ / 64, 32), 128, 0, stream>>>(Qb, Kb, vT, obuf);

  gemm_bt<64, 1><<<dim3(16, 32), 256, 0, stream>>>(obuf, woutT, bout, nullptr, nullptr, out,
                                                   MTOK, EMBED, EMBED);
}